// Round 2
// baseline (1986.000 us; speedup 1.0000x reference)
//
#include <hip/hip_runtime.h>
#include <cfloat>
#include <math.h>

// VQ-VAE encoder: B=16,S=512,D1=512,D2=256,NH=8,DK=32,DFF=1024,K=8192,L=3
// Round 2: replicate the numpy-fp32 reference numerics so the VQ argmin
// (quantized at ulp(256)=1.5e-5 with ties -> lowest index) matches bitwise.
//  - all GEMMs: sequential-k FMA chain (BLAS microkernel order), kc=384
//    block re-rounding for K>384 (OpenBLAS GEMM_Q), bias added after.
//  - GELU: f64 erf of f32 (x / fl32(sqrt(2))) -- scipy-equivalent.
//  - LayerNorm: numpy scalar pairwise-sum order (2x128 blocks, 8 strided
//    accumulators), 1/sqrtf (correctly rounded), op order mirrored.
//  - VQ dist: fl(A - 2*acc), A=||h||^2 (value-irrelevant mod grid), argmin
//    strict-< with lowest-index ties == np.argmin semantics.

#define NTOK 8192

// ---------------- numpy pairwise_sum order for 256 contiguous floats --------
// n=256: split into two 128-blocks; each block: 8 accumulators r[j] summing
// a[j], a[j+8], ..., a[j+120] sequentially; combine ((r0+r1)+(r2+r3))+((r4+r5)+(r6+r7));
// total = block0 + block1.  Executed by one 64-lane wave; xs is an LDS row.
__device__ __forceinline__ float np_pairwise256(const float* xs, int lane) {
  float r = 0.f;
  if (lane < 16) {
    const int b = lane >> 3, j = lane & 7;
    const float* p = xs + b * 128 + j;
    r = p[0];
#pragma unroll
    for (int i = 1; i < 16; i++) r += p[i * 8];
  }
  float r0 = __shfl(r, 0), r1 = __shfl(r, 1), r2 = __shfl(r, 2), r3 = __shfl(r, 3);
  float r4 = __shfl(r, 4), r5 = __shfl(r, 5), r6 = __shfl(r, 6), r7 = __shfl(r, 7);
  float s0 = ((r0 + r1) + (r2 + r3)) + ((r4 + r5) + (r6 + r7));
  float q0 = __shfl(r, 8), q1 = __shfl(r, 9), q2 = __shfl(r, 10), q3 = __shfl(r, 11);
  float q4 = __shfl(r, 12), q5 = __shfl(r, 13), q6 = __shfl(r, 14), q7 = __shfl(r, 15);
  float s1 = ((q0 + q1) + (q2 + q3)) + ((q4 + q5) + (q6 + q7));
  return s0 + s1;
}

__device__ __forceinline__ float gelu_np(float x) {
  const float SQRT2F = 1.4142135623730951f;  // np.sqrt(2).astype(f32)
  float xs = x / SQRT2F;                      // f32 division (correctly rounded)
  float e = (float)erf((double)xs);           // scipy-style: f64 erf, round to f32
  float t = 1.0f + e;
  return (0.5f * x) * t;                      // ((0.5*x)*t), 0.5*x exact
}

// ---------------- GEMM: C[M,N] = A[M,K] @ B[K,N] (+bias) (+GELU) ------------
// Sequential-k FMA per output with kc=384 block re-rounding (OpenBLAS order).
__global__ __launch_bounds__(256) void gemm_kernel(
    const float* __restrict__ A, const float* __restrict__ B,
    const float* __restrict__ bias, float* __restrict__ C,
    int M, int N, int K, int act)
{
  __shared__ float As[16][132];
  __shared__ float Bs[16][68];
  const int tid = threadIdx.x;
  const int tx = tid & 15, ty = tid >> 4;
  const int m0 = blockIdx.x * 128, n0 = blockIdx.y * 64;
  const int ar = tid >> 1;
  const int ak = (tid & 1) * 8;
  const int bk = tid >> 4;
  const int bn = (tid & 15) * 4;
  const float* Ap = A + (m0 + ar) * K + ak;
  const float* Bp = B + bk * N + n0 + bn;
  float acc[8][4] = {};
  float accb[8][4] = {};
  for (int k0 = 0; k0 < K; k0 += 16) {
    float4 a0 = *(const float4*)(Ap);
    float4 a1 = *(const float4*)(Ap + 4);
    float4 b0 = *(const float4*)(Bp);
    As[ak + 0][ar] = a0.x; As[ak + 1][ar] = a0.y;
    As[ak + 2][ar] = a0.z; As[ak + 3][ar] = a0.w;
    As[ak + 4][ar] = a1.x; As[ak + 5][ar] = a1.y;
    As[ak + 6][ar] = a1.z; As[ak + 7][ar] = a1.w;
    *(float4*)&Bs[bk][bn] = b0;
    __syncthreads();
#pragma unroll
    for (int kk = 0; kk < 16; kk++) {
      float4 a0v = *(const float4*)&As[kk][ty * 8];
      float4 a1v = *(const float4*)&As[kk][ty * 8 + 4];
      float4 bv = *(const float4*)&Bs[kk][tx * 4];
      float a[8] = {a0v.x, a0v.y, a0v.z, a0v.w, a1v.x, a1v.y, a1v.z, a1v.w};
      float bb[4] = {bv.x, bv.y, bv.z, bv.w};
#pragma unroll
      for (int i = 0; i < 8; i++)
#pragma unroll
        for (int j = 0; j < 4; j++) accb[i][j] = fmaf(a[i], bb[j], accb[i][j]);
    }
    __syncthreads();
    Ap += 16;
    Bp += 16 * N;
    // OpenBLAS kc=384 boundary: fold block sum into C accumulator (one add).
    if ((((k0 + 16) % 384) == 0) || (k0 + 16 == K)) {
#pragma unroll
      for (int i = 0; i < 8; i++)
#pragma unroll
        for (int j = 0; j < 4; j++) { acc[i][j] = acc[i][j] + accb[i][j]; accb[i][j] = 0.f; }
    }
  }
  float4 bb4 = make_float4(0.f, 0.f, 0.f, 0.f);
  if (bias) bb4 = *(const float4*)&bias[n0 + tx * 4];
#pragma unroll
  for (int i = 0; i < 8; i++) {
    int m = m0 + ty * 8 + i;
    float4 o;
    o.x = acc[i][0] + bb4.x;
    o.y = acc[i][1] + bb4.y;
    o.z = acc[i][2] + bb4.z;
    o.w = acc[i][3] + bb4.w;
    if (act == 1) {
      o.x = gelu_np(o.x); o.y = gelu_np(o.y);
      o.z = gelu_np(o.z); o.w = gelu_np(o.w);
    }
    *(float4*)&C[m * N + n0 + tx * 4] = o;
  }
}

// ---------------- attention: one query per thread, flash-style --------------
// (h-noise from attention is damped to ~1e-9 by the small ctx magnitude +
//  following LN, so online-softmax rounding differences are harmless.)
__global__ __launch_bounds__(256) void attn_kernel(
    const float* __restrict__ Q, const float* __restrict__ Kb,
    const float* __restrict__ Vb, float* __restrict__ ctx)
{
  __shared__ float Kc[128][32];
  __shared__ float Vc[128][32];
  const int bh = blockIdx.x;
  const int b = bh >> 3, h = bh & 7;
  const int s = blockIdx.y * 256 + threadIdx.x;
  const int base = (b * 512) * 256 + h * 32;

  float q[32];
  const float* qrow = Q + base + s * 256;
#pragma unroll
  for (int d = 0; d < 32; d += 4) {
    float4 t = *(const float4*)(qrow + d);
    q[d] = t.x; q[d + 1] = t.y; q[d + 2] = t.z; q[d + 3] = t.w;
  }
  float m = -1e30f, l = 0.f;
  float acc[32] = {};
  const float scale = 0.17677669529663687f;  // fl32(1/sqrt(32))

  for (int kc = 0; kc < 4; kc++) {
#pragma unroll
    for (int r = 0; r < 4; r++) {
      int ff = threadIdx.x + r * 256;
      int j = ff >> 3;
      int d0 = (ff & 7) * 4;
      int tok = kc * 128 + j;
      *(float4*)&Kc[j][d0] = *(const float4*)(Kb + base + tok * 256 + d0);
      *(float4*)&Vc[j][d0] = *(const float4*)(Vb + base + tok * 256 + d0);
    }
    __syncthreads();
    for (int j = 0; j < 128; j++) {
      const float* kr = &Kc[j][0];
      float s0 = 0.f, s1 = 0.f, s2 = 0.f, s3 = 0.f;
#pragma unroll
      for (int d = 0; d < 32; d += 4) {
        s0 = fmaf(q[d], kr[d], s0);
        s1 = fmaf(q[d + 1], kr[d + 1], s1);
        s2 = fmaf(q[d + 2], kr[d + 2], s2);
        s3 = fmaf(q[d + 3], kr[d + 3], s3);
      }
      float sc = ((s0 + s1) + (s2 + s3)) * scale;
      const float* vr = &Vc[j][0];
      if (sc <= m) {
        float p = expf(sc - m);
        l += p;
#pragma unroll
        for (int d = 0; d < 32; d++) acc[d] = fmaf(p, vr[d], acc[d]);
      } else {
        float corr = expf(m - sc);
        m = sc;
        l = fmaf(l, corr, 1.0f);
#pragma unroll
        for (int d = 0; d < 32; d++) acc[d] = fmaf(acc[d], corr, vr[d]);
      }
    }
    __syncthreads();
  }
  float inv = 1.f / l;
  float* crow = ctx + base + s * 256;
#pragma unroll
  for (int d = 0; d < 32; d += 4) {
    float4 o;
    o.x = acc[d] * inv; o.y = acc[d + 1] * inv;
    o.z = acc[d + 2] * inv; o.w = acc[d + 3] * inv;
    *(float4*)(crow + d) = o;
  }
}

// ---------------- fused residual + LayerNorm (numpy-order sums) -------------
__global__ __launch_bounds__(256) void ln_kernel(
    const float* __restrict__ X, const float* __restrict__ R,
    const float* __restrict__ g, const float* __restrict__ bt,
    float* __restrict__ Y, int hasR)
{
  __shared__ float rows[4][256];
  const int w = threadIdx.x >> 6, lane = threadIdx.x & 63;
  const int row = blockIdx.x * 4 + w;
  float4 xv = *(const float4*)(X + row * 256 + lane * 4);
  if (hasR) {
    float4 rv = *(const float4*)(R + row * 256 + lane * 4);
    xv.x += rv.x; xv.y += rv.y; xv.z += rv.z; xv.w += rv.w;
  }
  *(float4*)&rows[w][lane * 4] = xv;
  __syncthreads();
  float sum = np_pairwise256(rows[w], lane);
  float mean = sum * (1.0f / 256.0f);  // /256 exact (pow2)
  float dx = xv.x - mean, dy = xv.y - mean, dz = xv.z - mean, dw = xv.w - mean;
  __syncthreads();  // everyone done reading rows before overwrite
  float4 sq; sq.x = dx * dx; sq.y = dy * dy; sq.z = dz * dz; sq.w = dw * dw;
  *(float4*)&rows[w][lane * 4] = sq;
  __syncthreads();
  float vsum = np_pairwise256(rows[w], lane);
  float var = vsum * (1.0f / 256.0f);
  float inv = 1.0f / sqrtf(var + 1e-5f);  // np: 1/np.sqrt(v+eps), NOT rsqrtf
  float4 gv = *(const float4*)(g + lane * 4);
  float4 bv = *(const float4*)(bt + lane * 4);
  float4 o;
  o.x = ((dx * inv) * gv.x) + bv.x;
  o.y = ((dy * inv) * gv.y) + bv.y;
  o.z = ((dz * inv) * gv.z) + bv.z;
  o.w = ((dw * inv) * gv.w) + bv.w;
  *(float4*)(Y + row * 256 + lane * 4) = o;
}

// ---------------- A[t] = sum(h[t]**2) in numpy pairwise order ---------------
__global__ __launch_bounds__(256) void atok_kernel(
    const float* __restrict__ HN, float* __restrict__ Atok)
{
  __shared__ float rows[4][256];
  const int w = threadIdx.x >> 6, lane = threadIdx.x & 63;
  const int row = blockIdx.x * 4 + w;
  float4 v = *(const float4*)&HN[row * 256 + lane * 4];
  float4 sq; sq.x = v.x * v.x; sq.y = v.y * v.y; sq.z = v.z * v.z; sq.w = v.w * v.w;
  *(float4*)&rows[w][lane * 4] = sq;
  __syncthreads();
  float sum = np_pairwise256(rows[w], lane);
  if (lane == 0) Atok[row] = sum;
}

// ---------------- VQ pass 1: quantized dist fl(A - 2*acc), partial argmin ---
__global__ __launch_bounds__(256) void vq_partial_kernel(
    const float* __restrict__ H, const float* __restrict__ CB,
    const float* __restrict__ Atok, float* __restrict__ partV,
    int* __restrict__ partI)
{
  __shared__ float As[16][132];
  __shared__ float Bs[16][68];
  __shared__ float redV[128][17];
  __shared__ int redI[128][17];
  const int tid = threadIdx.x;
  const int tx = tid & 15, ty = tid >> 4;
  const int m0 = blockIdx.x * 128;
  const int cg0 = blockIdx.y * 512;
  const int ar = tid >> 1;
  const int ak = (tid & 1) * 8;
  const int bcr = tid >> 2;
  const int bck = (tid & 3) * 4;
  float At[8];
#pragma unroll
  for (int i = 0; i < 8; i++) At[i] = Atok[m0 + ty * 8 + i];
  float bestV[8];
  int bestI[8];
#pragma unroll
  for (int i = 0; i < 8; i++) { bestV[i] = FLT_MAX; bestI[i] = 0; }

  for (int ct = 0; ct < 8; ct++) {
    const int c0 = cg0 + ct * 64;
    float acc[8][4] = {};
    const float* Ap = H + (m0 + ar) * 256 + ak;
    const float* Bp = CB + (c0 + bcr) * 256 + bck;
    for (int k0 = 0; k0 < 256; k0 += 16) {
      float4 a0 = *(const float4*)(Ap);
      float4 a1 = *(const float4*)(Ap + 4);
      float4 c4 = *(const float4*)(Bp);
      As[ak + 0][ar] = a0.x; As[ak + 1][ar] = a0.y;
      As[ak + 2][ar] = a0.z; As[ak + 3][ar] = a0.w;
      As[ak + 4][ar] = a1.x; As[ak + 5][ar] = a1.y;
      As[ak + 6][ar] = a1.z; As[ak + 7][ar] = a1.w;
      Bs[bck + 0][bcr] = c4.x; Bs[bck + 1][bcr] = c4.y;
      Bs[bck + 2][bcr] = c4.z; Bs[bck + 3][bcr] = c4.w;
      __syncthreads();
#pragma unroll
      for (int kk = 0; kk < 16; kk++) {
        float4 a0v = *(const float4*)&As[kk][ty * 8];
        float4 a1v = *(const float4*)&As[kk][ty * 8 + 4];
        float4 bv = *(const float4*)&Bs[kk][tx * 4];
        float a[8] = {a0v.x, a0v.y, a0v.z, a0v.w, a1v.x, a1v.y, a1v.z, a1v.w};
        float bb[4] = {bv.x, bv.y, bv.z, bv.w};
#pragma unroll
        for (int i = 0; i < 8; i++)
#pragma unroll
          for (int j = 0; j < 4; j++) acc[i][j] = fmaf(a[i], bb[j], acc[i][j]);
      }
      __syncthreads();
      Ap += 16;
      Bp += 16;
    }
#pragma unroll
    for (int i = 0; i < 8; i++) {
#pragma unroll
      for (int j = 0; j < 4; j++) {
        int code = c0 + tx * 4 + j;
        // fl(A - 2*acc): 2*acc exact (exponent bump), single rounding on the
        // subtract -> bitwise == np's (sum1+sum2) - 2*mm (sum2 vanishes below
        // half-ulp(256)).
        float v = At[i] - 2.0f * acc[i][j];
        if (v < bestV[i]) { bestV[i] = v; bestI[i] = code; }
      }
    }
  }
#pragma unroll
  for (int i = 0; i < 8; i++) {
    redV[ty * 8 + i][tx] = bestV[i];
    redI[ty * 8 + i][tx] = bestI[i];
  }
  __syncthreads();
  if (tid < 128) {
    int r = tid;
    float bv = redV[r][0];
    int bi = redI[r][0];
    for (int t = 1; t < 16; t++) {
      float v = redV[r][t];
      int ii = redI[r][t];
      if (v < bv || (v == bv && ii < bi)) { bv = v; bi = ii; }
    }
    int token = m0 + r;
    partV[token * 16 + blockIdx.y] = bv;
    partI[token * 16 + blockIdx.y] = bi;
  }
}

// ---------------- VQ pass 2: final argmin, gather, loss, histogram ----------
__global__ __launch_bounds__(256) void vq_final_kernel(
    const float* __restrict__ partV, const int* __restrict__ partI,
    const float* __restrict__ HN, const float* __restrict__ CB,
    float* __restrict__ outQuant, float* __restrict__ outIdxF,
    int* __restrict__ idxInt, int* __restrict__ counts,
    float* __restrict__ lossAcc)
{
  const int w = threadIdx.x >> 6, lane = threadIdx.x & 63;
  const int t = blockIdx.x * 4 + w;
  float v = (lane < 16) ? partV[t * 16 + lane] : FLT_MAX;
  int i = (lane < 16) ? partI[t * 16 + lane] : 0x7fffffff;
#pragma unroll
  for (int off = 8; off; off >>= 1) {
    float ov = __shfl_xor(v, off);
    int oi = __shfl_xor(i, off);
    if (ov < v || (ov == v && oi < i)) { v = ov; i = oi; }
  }
  int idx = __shfl(i, 0);
  const float* c = CB + idx * 256;
  const float* hh = HN + t * 256;
  float4 cv = *(const float4*)(c + lane * 4);
  float4 hv = *(const float4*)(hh + lane * 4);
  *(float4*)(outQuant + t * 256 + lane * 4) = cv;
  float ex = cv.x - hv.x, ey = cv.y - hv.y, ez = cv.z - hv.z, ew = cv.w - hv.w;
  float se = ex * ex + ey * ey + ez * ez + ew * ew;
#pragma unroll
  for (int off = 32; off; off >>= 1) se += __shfl_xor(se, off);
  if (lane == 0) {
    outIdxF[t] = (float)idx;
    idxInt[t] = idx;
    atomicAdd(&counts[idx], 1);
    atomicAdd(lossAcc, se);
  }
}

// ---------------- VQ stats: loss finalize + perplexity ----------------------
__global__ __launch_bounds__(256) void vq_stats_kernel(
    const int* __restrict__ counts, const float* __restrict__ lossAcc,
    float* __restrict__ out)
{
  float ent = 0.f;
  for (int k = threadIdx.x; k < 8192; k += 256) {
    float p = (float)counts[k] * (1.0f / 8192.0f);
    ent += p * logf(p + 1e-10f);
  }
#pragma unroll
  for (int off = 32; off; off >>= 1) ent += __shfl_xor(ent, off);
  __shared__ float ws4[4];
  const int w = threadIdx.x >> 6, lane = threadIdx.x & 63;
  if (lane == 0) ws4[w] = ent;
  __syncthreads();
  if (threadIdx.x == 0) {
    float e = ws4[0] + ws4[1] + ws4[2] + ws4[3];
    out[2097152] = 1.25f * lossAcc[0] * (1.0f / 2097152.0f);
    out[2097153] = expf(-e);
  }
}

__global__ void zero_kernel(int* __restrict__ counts, float* __restrict__ lossAcc) {
  int i = blockIdx.x * 256 + threadIdx.x;
  if (i < 8192) counts[i] = 0;
  if (i == 0) lossAcc[0] = 0.f;
}

extern "C" void kernel_launch(void* const* d_in, const int* in_sizes, int n_in,
                              void* d_out, int out_size, void* d_ws, size_t ws_size,
                              hipStream_t stream) {
  const float* x = (const float*)d_in[0];
  const float* w_in = (const float*)d_in[1];
  const float* b_in = (const float*)d_in[2];
  const float* wq = (const float*)d_in[3];
  const float* bq = (const float*)d_in[4];
  const float* wk = (const float*)d_in[5];
  const float* bk = (const float*)d_in[6];
  const float* wv = (const float*)d_in[7];
  const float* bv = (const float*)d_in[8];
  const float* wo = (const float*)d_in[9];
  const float* bo = (const float*)d_in[10];
  const float* ln1g = (const float*)d_in[11];
  const float* ln1b = (const float*)d_in[12];
  const float* ln2g = (const float*)d_in[13];
  const float* ln2b = (const float*)d_in[14];
  const float* ff1w = (const float*)d_in[15];
  const float* ff1b = (const float*)d_in[16];
  const float* ff2w = (const float*)d_in[17];
  const float* ff2b = (const float*)d_in[18];
  const float* preg = (const float*)d_in[19];
  const float* preb = (const float*)d_in[20];
  const float* cb = (const float*)d_in[21];
  float* out = (float*)d_out;

  if (ws_size < (51ull << 20)) return;
  char* ws = (char*)d_ws;
  float* h = (float*)(ws + 0);                    // 8MB [8192,256]
  float* Qb = (float*)(ws + (8ull << 20));        // 8MB
  float* Kb2 = (float*)(ws + (16ull << 20));      // 8MB
  float* Vb = (float*)(ws + (24ull << 20));       // 8MB
  float* Cx = (float*)(ws + (32ull << 20));       // 8MB
  float* Ob = Qb;                                 // alias (Q dead after attn)
  float* F1 = Qb;                                 // alias 8..40MB [8192,1024]
  float* F2 = (float*)(ws + (40ull << 20));       // 8MB
  float* HN = F2;                                 // alias (F2 dead after ln2)
  float* Atok = (float*)(ws + (48ull << 20));     // 32KB
  float* partV = (float*)(ws + (49ull << 20));    // 512KB
  int* partI = (int*)(ws + (49ull << 20) + (512ull << 10));  // 512KB
  int* idxInt = (int*)(ws + (50ull << 20));       // 32KB
  int* counts = (int*)(ws + (50ull << 20) + (64ull << 10));  // 32KB
  float* lossAcc = (float*)(ws + (50ull << 20) + (128ull << 10));

  zero_kernel<<<32, 256, 0, stream>>>(counts, lossAcc);

  // h = x @ w_in + b_in   [8192,512]x[512,256]
  gemm_kernel<<<dim3(64, 4), 256, 0, stream>>>(x, w_in, b_in, h, NTOK, 256, 512, 0);

  for (int i = 0; i < 3; i++) {
    const float* wqi = wq + i * 65536;
    const float* wki = wk + i * 65536;
    const float* wvi = wv + i * 65536;
    const float* woi = wo + i * 65536;
    gemm_kernel<<<dim3(64, 4), 256, 0, stream>>>(h, wqi, bq + i * 256, Qb, NTOK, 256, 256, 0);
    gemm_kernel<<<dim3(64, 4), 256, 0, stream>>>(h, wki, bk + i * 256, Kb2, NTOK, 256, 256, 0);
    gemm_kernel<<<dim3(64, 4), 256, 0, stream>>>(h, wvi, bv + i * 256, Vb, NTOK, 256, 256, 0);
    attn_kernel<<<dim3(128, 2), 256, 0, stream>>>(Qb, Kb2, Vb, Cx);
    gemm_kernel<<<dim3(64, 4), 256, 0, stream>>>(Cx, woi, bo + i * 256, Ob, NTOK, 256, 256, 0);
    ln_kernel<<<2048, 256, 0, stream>>>(h, Ob, ln1g + i * 256, ln1b + i * 256, h, 1);
    gemm_kernel<<<dim3(64, 16), 256, 0, stream>>>(h, ff1w + i * 262144, ff1b + i * 1024, F1, NTOK, 1024, 256, 1);
    gemm_kernel<<<dim3(64, 4), 256, 0, stream>>>(F1, ff2w + i * 262144, ff2b + i * 256, F2, NTOK, 256, 1024, 0);
    ln_kernel<<<2048, 256, 0, stream>>>(h, F2, ln2g + i * 256, ln2b + i * 256, h, 1);
  }
  ln_kernel<<<2048, 256, 0, stream>>>(h, nullptr, preg, preb, HN, 0);

  atok_kernel<<<2048, 256, 0, stream>>>(HN, Atok);
  vq_partial_kernel<<<dim3(64, 16), 256, 0, stream>>>(HN, cb, Atok, partV, partI);
  vq_final_kernel<<<2048, 256, 0, stream>>>(partV, partI, HN, cb,
                                            out, out + 2097154, idxInt, counts, lossAcc);
  vq_stats_kernel<<<1, 256, 0, stream>>>(counts, lossAcc, out);
}

// Round 3
// 1647.060 us; speedup vs baseline: 1.2058x; 1.2058x over previous
//
#include <hip/hip_runtime.h>
#include <cfloat>
#include <math.h>

// VQ-VAE encoder: B=16,S=512,D1=512,D2=256,NH=8,DK=32,DFF=1024,K=8192,L=3
// Round 3: perf pass. Numerics contract (DO NOT BREAK — validated round 2):
//  - every GEMM output element: sequential-k FMA chain, kc=384 re-round folds
//  - LN: numpy pairwise-256 order, 1/sqrtf; GELU: f64 erf; VQ dist fl(A-2acc)
//  - attention has rounding freedom (perturbs h at ~1e-9; argmin stable)
// Perf changes: branch-free exp attention (scores bounded |s|<=0.58 by
// Cauchy-Schwarz), 64x64 dbuf GEMM (2+ blocks/CU), vq 8x8 micro-tile with
// shuffle argmin-reduce (half the barriers, no red-LDS).

#define NTOK 8192

// ---------------- numpy pairwise_sum order for 256 contiguous floats --------
__device__ __forceinline__ float np_pairwise256(const float* xs, int lane) {
  float r = 0.f;
  if (lane < 16) {
    const int b = lane >> 3, j = lane & 7;
    const float* p = xs + b * 128 + j;
    r = p[0];
#pragma unroll
    for (int i = 1; i < 16; i++) r += p[i * 8];
  }
  float r0 = __shfl(r, 0), r1 = __shfl(r, 1), r2 = __shfl(r, 2), r3 = __shfl(r, 3);
  float r4 = __shfl(r, 4), r5 = __shfl(r, 5), r6 = __shfl(r, 6), r7 = __shfl(r, 7);
  float s0 = ((r0 + r1) + (r2 + r3)) + ((r4 + r5) + (r6 + r7));
  float q0 = __shfl(r, 8), q1 = __shfl(r, 9), q2 = __shfl(r, 10), q3 = __shfl(r, 11);
  float q4 = __shfl(r, 12), q5 = __shfl(r, 13), q6 = __shfl(r, 14), q7 = __shfl(r, 15);
  float s1 = ((q0 + q1) + (q2 + q3)) + ((q4 + q5) + (q6 + q7));
  return s0 + s1;
}

__device__ __forceinline__ float gelu_np(float x) {
  const float SQRT2F = 1.4142135623730951f;
  float xs = x / SQRT2F;
  float e = (float)erf((double)xs);
  float t = 1.0f + e;
  return (0.5f * x) * t;
}

// ---------------- GEMM 64x64 tile, 4x4 micro, double-buffered LDS -----------
// C[M,N] = A[M,K]@B[K,N] (+bias)(+GELU); sequential-k FMA, kc=384 folds.
__global__ __launch_bounds__(256) void gemm64_kernel(
    const float* __restrict__ A, const float* __restrict__ B,
    const float* __restrict__ bias, float* __restrict__ C,
    int M, int N, int K, int act)
{
  __shared__ float As[2][16][68];
  __shared__ float Bs[2][16][68];
  const int tid = threadIdx.x;
  const int tx = tid & 15, ty = tid >> 4;
  const int m0 = blockIdx.x * 64, n0 = blockIdx.y * 64;
  const int ar = tid >> 2;            // 0..63 row of A tile
  const int ak = (tid & 3) * 4;       // k offset
  const int br = tid >> 4;            // 0..15 k row of B tile
  const int bn = (tid & 15) * 4;      // col offset
  const float* Ap = A + (m0 + ar) * K + ak;
  const float* Bp = B + br * N + n0 + bn;
  float acc[4][4] = {};
  float accb[4][4] = {};
  const int nk = K >> 4;

  float4 aR = *(const float4*)(Ap);
  float4 bR = *(const float4*)(Bp);
  As[0][ak + 0][ar] = aR.x; As[0][ak + 1][ar] = aR.y;
  As[0][ak + 2][ar] = aR.z; As[0][ak + 3][ar] = aR.w;
  *(float4*)&Bs[0][br][bn] = bR;

  for (int t = 0; t < nk; t++) {
    const int p = t & 1;
    __syncthreads();
    if (t + 1 < nk) {
      aR = *(const float4*)(Ap + (t + 1) * 16);
      bR = *(const float4*)(Bp + (t + 1) * 16 * N);
    }
#pragma unroll
    for (int kk = 0; kk < 16; kk++) {
      float4 av = *(const float4*)&As[p][kk][ty * 4];
      float4 bv = *(const float4*)&Bs[p][kk][tx * 4];
      float a[4] = {av.x, av.y, av.z, av.w};
      float b[4] = {bv.x, bv.y, bv.z, bv.w};
#pragma unroll
      for (int i = 0; i < 4; i++)
#pragma unroll
        for (int j = 0; j < 4; j++) accb[i][j] = fmaf(a[i], b[j], accb[i][j]);
    }
    // kc=384 fold boundaries (and final)
    if (((((t + 1) << 4) % 384) == 0) || (t + 1 == nk)) {
#pragma unroll
      for (int i = 0; i < 4; i++)
#pragma unroll
        for (int j = 0; j < 4; j++) { acc[i][j] += accb[i][j]; accb[i][j] = 0.f; }
    }
    if (t + 1 < nk) {
      const int q = p ^ 1;
      As[q][ak + 0][ar] = aR.x; As[q][ak + 1][ar] = aR.y;
      As[q][ak + 2][ar] = aR.z; As[q][ak + 3][ar] = aR.w;
      *(float4*)&Bs[q][br][bn] = bR;
    }
  }
  float4 bb4 = make_float4(0.f, 0.f, 0.f, 0.f);
  if (bias) bb4 = *(const float4*)&bias[n0 + tx * 4];
#pragma unroll
  for (int i = 0; i < 4; i++) {
    float4 o;
    o.x = acc[i][0] + bb4.x;
    o.y = acc[i][1] + bb4.y;
    o.z = acc[i][2] + bb4.z;
    o.w = acc[i][3] + bb4.w;
    if (act == 1) {
      o.x = gelu_np(o.x); o.y = gelu_np(o.y);
      o.z = gelu_np(o.z); o.w = gelu_np(o.w);
    }
    *(float4*)&C[(m0 + ty * 4 + i) * N + n0 + tx * 4] = o;
  }
}

// ---------------- attention: branch-free exp, 1 query/thread ----------------
// |score| <= |q||k|/sqrt(32) <= 0.58 (LN'd h, 0.02-scale weights) -> no max
// subtraction needed; exp cannot overflow. ctx = (sum p*v)/(sum p).
__global__ __launch_bounds__(256) void attn_kernel(
    const float* __restrict__ Q, const float* __restrict__ Kb,
    const float* __restrict__ Vb, float* __restrict__ ctx)
{
  __shared__ float Kc[128][32];
  __shared__ float Vc[128][32];
  const int bh = blockIdx.x;
  const int b = bh >> 3, h = bh & 7;
  const int s = blockIdx.y * 256 + threadIdx.x;
  const int base = (b * 512) * 256 + h * 32;

  float q[32];
  const float* qrow = Q + base + s * 256;
#pragma unroll
  for (int d = 0; d < 32; d += 4) {
    float4 t = *(const float4*)(qrow + d);
    q[d] = t.x; q[d + 1] = t.y; q[d + 2] = t.z; q[d + 3] = t.w;
  }
  float l = 0.f;
  float acc[32] = {};
  const float scale = 0.17677669529663687f;  // fl32(1/sqrt(32))

  for (int kc = 0; kc < 4; kc++) {
#pragma unroll
    for (int r = 0; r < 4; r++) {
      int ff = threadIdx.x + r * 256;
      int j = ff >> 3;
      int d0 = (ff & 7) * 4;
      int tok = kc * 128 + j;
      *(float4*)&Kc[j][d0] = *(const float4*)(Kb + base + tok * 256 + d0);
      *(float4*)&Vc[j][d0] = *(const float4*)(Vb + base + tok * 256 + d0);
    }
    __syncthreads();
#pragma unroll 2
    for (int j = 0; j < 128; j += 2) {
      const float* k0r = &Kc[j][0];
      const float* k1r = &Kc[j + 1][0];
      float a0 = 0.f, a1 = 0.f, a2 = 0.f, a3 = 0.f;
      float b0 = 0.f, b1 = 0.f, b2 = 0.f, b3 = 0.f;
#pragma unroll
      for (int d = 0; d < 32; d += 4) {
        a0 = fmaf(q[d], k0r[d], a0);
        a1 = fmaf(q[d + 1], k0r[d + 1], a1);
        a2 = fmaf(q[d + 2], k0r[d + 2], a2);
        a3 = fmaf(q[d + 3], k0r[d + 3], a3);
        b0 = fmaf(q[d], k1r[d], b0);
        b1 = fmaf(q[d + 1], k1r[d + 1], b1);
        b2 = fmaf(q[d + 2], k1r[d + 2], b2);
        b3 = fmaf(q[d + 3], k1r[d + 3], b3);
      }
      float p0 = expf(((a0 + a1) + (a2 + a3)) * scale);
      float p1 = expf(((b0 + b1) + (b2 + b3)) * scale);
      l += p0;
      l += p1;
      const float* v0r = &Vc[j][0];
      const float* v1r = &Vc[j + 1][0];
#pragma unroll
      for (int d = 0; d < 32; d++)
        acc[d] = fmaf(p1, v1r[d], fmaf(p0, v0r[d], acc[d]));
    }
    __syncthreads();
  }
  float inv = 1.f / l;
  float* crow = ctx + base + s * 256;
#pragma unroll
  for (int d = 0; d < 32; d += 4) {
    float4 o;
    o.x = acc[d] * inv; o.y = acc[d + 1] * inv;
    o.z = acc[d + 2] * inv; o.w = acc[d + 3] * inv;
    *(float4*)(crow + d) = o;
  }
}

// ---------------- fused residual + LayerNorm (numpy-order sums) -------------
__global__ __launch_bounds__(256) void ln_kernel(
    const float* __restrict__ X, const float* __restrict__ R,
    const float* __restrict__ g, const float* __restrict__ bt,
    float* __restrict__ Y, int hasR)
{
  __shared__ float rows[4][256];
  const int w = threadIdx.x >> 6, lane = threadIdx.x & 63;
  const int row = blockIdx.x * 4 + w;
  float4 xv = *(const float4*)(X + row * 256 + lane * 4);
  if (hasR) {
    float4 rv = *(const float4*)(R + row * 256 + lane * 4);
    xv.x += rv.x; xv.y += rv.y; xv.z += rv.z; xv.w += rv.w;
  }
  *(float4*)&rows[w][lane * 4] = xv;
  __syncthreads();
  float sum = np_pairwise256(rows[w], lane);
  float mean = sum * (1.0f / 256.0f);
  float dx = xv.x - mean, dy = xv.y - mean, dz = xv.z - mean, dw = xv.w - mean;
  __syncthreads();
  float4 sq; sq.x = dx * dx; sq.y = dy * dy; sq.z = dz * dz; sq.w = dw * dw;
  *(float4*)&rows[w][lane * 4] = sq;
  __syncthreads();
  float vsum = np_pairwise256(rows[w], lane);
  float var = vsum * (1.0f / 256.0f);
  float inv = 1.0f / sqrtf(var + 1e-5f);
  float4 gv = *(const float4*)(g + lane * 4);
  float4 bv = *(const float4*)(bt + lane * 4);
  float4 o;
  o.x = ((dx * inv) * gv.x) + bv.x;
  o.y = ((dy * inv) * gv.y) + bv.y;
  o.z = ((dz * inv) * gv.z) + bv.z;
  o.w = ((dw * inv) * gv.w) + bv.w;
  *(float4*)(Y + row * 256 + lane * 4) = o;
}

// ---------------- A[t] = sum(h[t]**2) in numpy pairwise order ---------------
__global__ __launch_bounds__(256) void atok_kernel(
    const float* __restrict__ HN, float* __restrict__ Atok)
{
  __shared__ float rows[4][256];
  const int w = threadIdx.x >> 6, lane = threadIdx.x & 63;
  const int row = blockIdx.x * 4 + w;
  float4 v = *(const float4*)&HN[row * 256 + lane * 4];
  float4 sq; sq.x = v.x * v.x; sq.y = v.y * v.y; sq.z = v.z * v.z; sq.w = v.w * v.w;
  *(float4*)&rows[w][lane * 4] = sq;
  __syncthreads();
  float sum = np_pairwise256(rows[w], lane);
  if (lane == 0) Atok[row] = sum;
}

// ---------------- VQ pass 1: 128 tok x 512 codes/block, 8x8 micro -----------
__global__ __launch_bounds__(256) void vq_partial_kernel(
    const float* __restrict__ H, const float* __restrict__ CB,
    const float* __restrict__ Atok, float* __restrict__ partV,
    int* __restrict__ partI)
{
  __shared__ float As[16][132];
  __shared__ float Bs[16][132];
  const int tid = threadIdx.x;
  const int tx = tid & 15, ty = tid >> 4;
  const int m0 = blockIdx.x * 128;
  const int cg0 = blockIdx.y * 512;
  const int ar = tid >> 1;        // 0..127 (token row / code row for staging)
  const int ak = (tid & 1) * 8;   // 0 or 8
  float At[8];
#pragma unroll
  for (int i = 0; i < 8; i++) At[i] = Atok[m0 + ty * 8 + i];
  float bestV[8];
  int bestI[8];
#pragma unroll
  for (int i = 0; i < 8; i++) { bestV[i] = FLT_MAX; bestI[i] = 0; }

  for (int ct = 0; ct < 4; ct++) {
    const int c0 = cg0 + ct * 128;
    float acc[8][8] = {};
    const float* Ap = H + (m0 + ar) * 256 + ak;
    const float* Bp = CB + (c0 + ar) * 256 + ak;
    for (int k0 = 0; k0 < 256; k0 += 16) {
      float4 a0 = *(const float4*)(Ap);
      float4 a1 = *(const float4*)(Ap + 4);
      float4 c0v = *(const float4*)(Bp);
      float4 c1v = *(const float4*)(Bp + 4);
      As[ak + 0][ar] = a0.x; As[ak + 1][ar] = a0.y;
      As[ak + 2][ar] = a0.z; As[ak + 3][ar] = a0.w;
      As[ak + 4][ar] = a1.x; As[ak + 5][ar] = a1.y;
      As[ak + 6][ar] = a1.z; As[ak + 7][ar] = a1.w;
      Bs[ak + 0][ar] = c0v.x; Bs[ak + 1][ar] = c0v.y;
      Bs[ak + 2][ar] = c0v.z; Bs[ak + 3][ar] = c0v.w;
      Bs[ak + 4][ar] = c1v.x; Bs[ak + 5][ar] = c1v.y;
      Bs[ak + 6][ar] = c1v.z; Bs[ak + 7][ar] = c1v.w;
      __syncthreads();
#pragma unroll
      for (int kk = 0; kk < 16; kk++) {
        float4 av0 = *(const float4*)&As[kk][ty * 8];
        float4 av1 = *(const float4*)&As[kk][ty * 8 + 4];
        float4 bv0 = *(const float4*)&Bs[kk][tx * 8];
        float4 bv1 = *(const float4*)&Bs[kk][tx * 8 + 4];
        float a[8] = {av0.x, av0.y, av0.z, av0.w, av1.x, av1.y, av1.z, av1.w};
        float b[8] = {bv0.x, bv0.y, bv0.z, bv0.w, bv1.x, bv1.y, bv1.z, bv1.w};
#pragma unroll
        for (int i = 0; i < 8; i++)
#pragma unroll
          for (int j = 0; j < 8; j++) acc[i][j] = fmaf(a[i], b[j], acc[i][j]);
      }
      __syncthreads();
      Ap += 16;
      Bp += 16;
    }
#pragma unroll
    for (int i = 0; i < 8; i++) {
#pragma unroll
      for (int j = 0; j < 8; j++) {
        int code = c0 + tx * 8 + j;
        float v = At[i] - 2.0f * acc[i][j];  // fl(A - 2*acc), single rounding
        if (v < bestV[i]) { bestV[i] = v; bestI[i] = code; }
      }
    }
  }
  // argmin reduce across the 16 tx lanes (contiguous within wave)
#pragma unroll
  for (int i = 0; i < 8; i++) {
    float v = bestV[i];
    int ii = bestI[i];
#pragma unroll
    for (int off = 1; off < 16; off <<= 1) {
      float ov = __shfl_xor(v, off);
      int oi = __shfl_xor(ii, off);
      if (ov < v || (ov == v && oi < ii)) { v = ov; ii = oi; }
    }
    if (tx == 0) {
      int token = m0 + ty * 8 + i;
      partV[token * 16 + blockIdx.y] = v;
      partI[token * 16 + blockIdx.y] = ii;
    }
  }
}

// ---------------- VQ pass 2: final argmin, gather, loss, histogram ----------
__global__ __launch_bounds__(256) void vq_final_kernel(
    const float* __restrict__ partV, const int* __restrict__ partI,
    const float* __restrict__ HN, const float* __restrict__ CB,
    float* __restrict__ outQuant, float* __restrict__ outIdxF,
    int* __restrict__ idxInt, int* __restrict__ counts,
    float* __restrict__ lossAcc)
{
  const int w = threadIdx.x >> 6, lane = threadIdx.x & 63;
  const int t = blockIdx.x * 4 + w;
  float v = (lane < 16) ? partV[t * 16 + lane] : FLT_MAX;
  int i = (lane < 16) ? partI[t * 16 + lane] : 0x7fffffff;
#pragma unroll
  for (int off = 8; off; off >>= 1) {
    float ov = __shfl_xor(v, off);
    int oi = __shfl_xor(i, off);
    if (ov < v || (ov == v && oi < i)) { v = ov; i = oi; }
  }
  int idx = __shfl(i, 0);
  const float* c = CB + idx * 256;
  const float* hh = HN + t * 256;
  float4 cv = *(const float4*)(c + lane * 4);
  float4 hv = *(const float4*)(hh + lane * 4);
  *(float4*)(outQuant + t * 256 + lane * 4) = cv;
  float ex = cv.x - hv.x, ey = cv.y - hv.y, ez = cv.z - hv.z, ew = cv.w - hv.w;
  float se = ex * ex + ey * ey + ez * ez + ew * ew;
#pragma unroll
  for (int off = 32; off; off >>= 1) se += __shfl_xor(se, off);
  if (lane == 0) {
    outIdxF[t] = (float)idx;
    idxInt[t] = idx;
    atomicAdd(&counts[idx], 1);
    atomicAdd(lossAcc, se);
  }
}

// ---------------- VQ stats: loss finalize + perplexity ----------------------
__global__ __launch_bounds__(256) void vq_stats_kernel(
    const int* __restrict__ counts, const float* __restrict__ lossAcc,
    float* __restrict__ out)
{
  float ent = 0.f;
  for (int k = threadIdx.x; k < 8192; k += 256) {
    float p = (float)counts[k] * (1.0f / 8192.0f);
    ent += p * logf(p + 1e-10f);
  }
#pragma unroll
  for (int off = 32; off; off >>= 1) ent += __shfl_xor(ent, off);
  __shared__ float ws4[4];
  const int w = threadIdx.x >> 6, lane = threadIdx.x & 63;
  if (lane == 0) ws4[w] = ent;
  __syncthreads();
  if (threadIdx.x == 0) {
    float e = ws4[0] + ws4[1] + ws4[2] + ws4[3];
    out[2097152] = 1.25f * lossAcc[0] * (1.0f / 2097152.0f);
    out[2097153] = expf(-e);
  }
}

__global__ void zero_kernel(int* __restrict__ counts, float* __restrict__ lossAcc) {
  int i = blockIdx.x * 256 + threadIdx.x;
  if (i < 8192) counts[i] = 0;
  if (i == 0) lossAcc[0] = 0.f;
}

extern "C" void kernel_launch(void* const* d_in, const int* in_sizes, int n_in,
                              void* d_out, int out_size, void* d_ws, size_t ws_size,
                              hipStream_t stream) {
  const float* x = (const float*)d_in[0];
  const float* w_in = (const float*)d_in[1];
  const float* b_in = (const float*)d_in[2];
  const float* wq = (const float*)d_in[3];
  const float* bq = (const float*)d_in[4];
  const float* wk = (const float*)d_in[5];
  const float* bk = (const float*)d_in[6];
  const float* wv = (const float*)d_in[7];
  const float* bv = (const float*)d_in[8];
  const float* wo = (const float*)d_in[9];
  const float* bo = (const float*)d_in[10];
  const float* ln1g = (const float*)d_in[11];
  const float* ln1b = (const float*)d_in[12];
  const float* ln2g = (const float*)d_in[13];
  const float* ln2b = (const float*)d_in[14];
  const float* ff1w = (const float*)d_in[15];
  const float* ff1b = (const float*)d_in[16];
  const float* ff2w = (const float*)d_in[17];
  const float* ff2b = (const float*)d_in[18];
  const float* preg = (const float*)d_in[19];
  const float* preb = (const float*)d_in[20];
  const float* cb = (const float*)d_in[21];
  float* out = (float*)d_out;

  if (ws_size < (51ull << 20)) return;
  char* ws = (char*)d_ws;
  float* h = (float*)(ws + 0);                    // 8MB [8192,256]
  float* Qb = (float*)(ws + (8ull << 20));        // 8MB
  float* Kb2 = (float*)(ws + (16ull << 20));      // 8MB
  float* Vb = (float*)(ws + (24ull << 20));       // 8MB
  float* Cx = (float*)(ws + (32ull << 20));       // 8MB
  float* Ob = Qb;                                 // alias (Q dead after attn)
  float* F1 = Qb;                                 // alias 8..40MB [8192,1024]
  float* F2 = (float*)(ws + (40ull << 20));       // 8MB
  float* HN = F2;                                 // alias (F2 dead after ln2)
  float* Atok = (float*)(ws + (48ull << 20));     // 32KB
  float* partV = (float*)(ws + (49ull << 20));    // 512KB
  int* partI = (int*)(ws + (49ull << 20) + (512ull << 10));  // 512KB
  int* idxInt = (int*)(ws + (50ull << 20));       // 32KB
  int* counts = (int*)(ws + (50ull << 20) + (64ull << 10));  // 32KB
  float* lossAcc = (float*)(ws + (50ull << 20) + (128ull << 10));

  zero_kernel<<<32, 256, 0, stream>>>(counts, lossAcc);

  // h = x @ w_in + b_in   [8192,512]x[512,256]
  gemm64_kernel<<<dim3(128, 4), 256, 0, stream>>>(x, w_in, b_in, h, NTOK, 256, 512, 0);

  for (int i = 0; i < 3; i++) {
    const float* wqi = wq + i * 65536;
    const float* wki = wk + i * 65536;
    const float* wvi = wv + i * 65536;
    const float* woi = wo + i * 65536;
    gemm64_kernel<<<dim3(128, 4), 256, 0, stream>>>(h, wqi, bq + i * 256, Qb, NTOK, 256, 256, 0);
    gemm64_kernel<<<dim3(128, 4), 256, 0, stream>>>(h, wki, bk + i * 256, Kb2, NTOK, 256, 256, 0);
    gemm64_kernel<<<dim3(128, 4), 256, 0, stream>>>(h, wvi, bv + i * 256, Vb, NTOK, 256, 256, 0);
    attn_kernel<<<dim3(128, 2), 256, 0, stream>>>(Qb, Kb2, Vb, Cx);
    gemm64_kernel<<<dim3(128, 4), 256, 0, stream>>>(Cx, woi, bo + i * 256, Ob, NTOK, 256, 256, 0);
    ln_kernel<<<2048, 256, 0, stream>>>(h, Ob, ln1g + i * 256, ln1b + i * 256, h, 1);
    gemm64_kernel<<<dim3(128, 16), 256, 0, stream>>>(h, ff1w + i * 262144, ff1b + i * 1024, F1, NTOK, 1024, 256, 1);
    gemm64_kernel<<<dim3(128, 4), 256, 0, stream>>>(F1, ff2w + i * 262144, ff2b + i * 256, F2, NTOK, 256, 1024, 0);
    ln_kernel<<<2048, 256, 0, stream>>>(h, F2, ln2g + i * 256, ln2b + i * 256, h, 1);
  }
  ln_kernel<<<2048, 256, 0, stream>>>(h, nullptr, preg, preb, HN, 0);

  atok_kernel<<<2048, 256, 0, stream>>>(HN, Atok);
  vq_partial_kernel<<<dim3(64, 16), 256, 0, stream>>>(HN, cb, Atok, partV, partI);
  vq_final_kernel<<<2048, 256, 0, stream>>>(partV, partI, HN, cb,
                                            out, out + 2097154, idxInt, counts, lossAcc);
  vq_stats_kernel<<<1, 256, 0, stream>>>(counts, lossAcc, out);
}

// Round 4
// 1598.252 us; speedup vs baseline: 1.2426x; 1.0305x over previous
//
#include <hip/hip_runtime.h>
#include <cfloat>
#include <math.h>

// VQ-VAE encoder: B=16,S=512,D1=512,D2=256,NH=8,DK=32,DFF=1024,K=8192,L=3
// Round 4: numerics contract (DO NOT BREAK — validated rounds 2-3):
//  - every GEMM output element: sequential-k FMA chain, kc=384 re-round folds
//  - LN: numpy pairwise-256 order, 1/sqrtf; GELU: f64 erf; VQ dist fl(A-2acc)
//  - attention has rounding freedom (perturbs h at ~1e-9; argmin stable)
// Perf changes this round:
//  - split B-fragment (tx*4 / 64+tx*4) -> 2-way LDS aliasing (free) instead of
//    4-way conflicts in all 8x8 micro-tiles (vq_partial was 16% conflict cycles)
//  - gemm128: 128x128 tile, 8x8 micro (82 TF-class structure from vq_partial)
//    used for fused-QKV (one launch, grid (64,6)) and FF1 (grid (64,8))

#define NTOK 8192

// ---------------- numpy pairwise_sum order for 256 contiguous floats --------
__device__ __forceinline__ float np_pairwise256(const float* xs, int lane) {
  float r = 0.f;
  if (lane < 16) {
    const int b = lane >> 3, j = lane & 7;
    const float* p = xs + b * 128 + j;
    r = p[0];
#pragma unroll
    for (int i = 1; i < 16; i++) r += p[i * 8];
  }
  float r0 = __shfl(r, 0), r1 = __shfl(r, 1), r2 = __shfl(r, 2), r3 = __shfl(r, 3);
  float r4 = __shfl(r, 4), r5 = __shfl(r, 5), r6 = __shfl(r, 6), r7 = __shfl(r, 7);
  float s0 = ((r0 + r1) + (r2 + r3)) + ((r4 + r5) + (r6 + r7));
  float q0 = __shfl(r, 8), q1 = __shfl(r, 9), q2 = __shfl(r, 10), q3 = __shfl(r, 11);
  float q4 = __shfl(r, 12), q5 = __shfl(r, 13), q6 = __shfl(r, 14), q7 = __shfl(r, 15);
  float s1 = ((q0 + q1) + (q2 + q3)) + ((q4 + q5) + (q6 + q7));
  return s0 + s1;
}

__device__ __forceinline__ float gelu_np(float x) {
  const float SQRT2F = 1.4142135623730951f;
  float xs = x / SQRT2F;
  float e = (float)erf((double)xs);
  float t = 1.0f + e;
  return (0.5f * x) * t;
}

// ---------------- gemm128 core: 128x128 tile, 8x8 micro, 256 threads --------
// C[M,N] tile at (m0,n0) = A[M,K] @ Bw[K,N] + bias (+GELU). K<=384 (no fold
// boundary inside; single sequential-k chain, fold at end == numpy bitwise).
__device__ __forceinline__ void gemm128_core(
    const float* __restrict__ A, const float* __restrict__ Bw,
    const float* __restrict__ bias, float* __restrict__ C,
    int M, int N, int K, int act, int m0, int n0)
{
  __shared__ float As[16][132];
  __shared__ float Bs[16][132];
  const int tid = threadIdx.x;
  const int tx = tid & 15, ty = tid >> 4;
  const int ar = tid >> 1;         // 0..127 token row
  const int ak = (tid & 1) * 8;    // 0 or 8
  const int brr = tid >> 5;        // 0..7 (k row)
  const int bnn = (tid & 31) * 4;  // 0..124 (col)
  float accb[8][8] = {};
  const float* Ap = A + (m0 + ar) * K + ak;
  const float* Bp = Bw + brr * N + n0 + bnn;

  for (int k0 = 0; k0 < K; k0 += 16) {
    float4 a0 = *(const float4*)(Ap);
    float4 a1 = *(const float4*)(Ap + 4);
    float4 b0 = *(const float4*)(Bp);
    float4 b1 = *(const float4*)(Bp + 8 * N);
    As[ak + 0][ar] = a0.x; As[ak + 1][ar] = a0.y;
    As[ak + 2][ar] = a0.z; As[ak + 3][ar] = a0.w;
    As[ak + 4][ar] = a1.x; As[ak + 5][ar] = a1.y;
    As[ak + 6][ar] = a1.z; As[ak + 7][ar] = a1.w;
    *(float4*)&Bs[brr][bnn] = b0;
    *(float4*)&Bs[brr + 8][bnn] = b1;
    __syncthreads();
#pragma unroll
    for (int kk = 0; kk < 16; kk++) {
      float4 av0 = *(const float4*)&As[kk][ty * 8];
      float4 av1 = *(const float4*)&As[kk][ty * 8 + 4];
      float4 bv0 = *(const float4*)&Bs[kk][tx * 4];        // banks 2-way: free
      float4 bv1 = *(const float4*)&Bs[kk][64 + tx * 4];   // banks 2-way: free
      float a[8] = {av0.x, av0.y, av0.z, av0.w, av1.x, av1.y, av1.z, av1.w};
      float b[8] = {bv0.x, bv0.y, bv0.z, bv0.w, bv1.x, bv1.y, bv1.z, bv1.w};
#pragma unroll
      for (int i = 0; i < 8; i++)
#pragma unroll
        for (int j = 0; j < 8; j++) accb[i][j] = fmaf(a[i], b[j], accb[i][j]);
    }
    __syncthreads();
    Ap += 16;
    Bp += 16 * N;
  }
  float4 bbl = make_float4(0.f, 0.f, 0.f, 0.f);
  float4 bbh = make_float4(0.f, 0.f, 0.f, 0.f);
  if (bias) {
    bbl = *(const float4*)&bias[n0 + tx * 4];
    bbh = *(const float4*)&bias[n0 + 64 + tx * 4];
  }
#pragma unroll
  for (int i = 0; i < 8; i++) {
    const int m = m0 + ty * 8 + i;
    float4 lo, hi;
    lo.x = accb[i][0] + bbl.x; lo.y = accb[i][1] + bbl.y;
    lo.z = accb[i][2] + bbl.z; lo.w = accb[i][3] + bbl.w;
    hi.x = accb[i][4] + bbh.x; hi.y = accb[i][5] + bbh.y;
    hi.z = accb[i][6] + bbh.z; hi.w = accb[i][7] + bbh.w;
    if (act == 1) {
      lo.x = gelu_np(lo.x); lo.y = gelu_np(lo.y);
      lo.z = gelu_np(lo.z); lo.w = gelu_np(lo.w);
      hi.x = gelu_np(hi.x); hi.y = gelu_np(hi.y);
      hi.z = gelu_np(hi.z); hi.w = gelu_np(hi.w);
    }
    *(float4*)&C[m * N + n0 + tx * 4] = lo;
    *(float4*)&C[m * N + n0 + 64 + tx * 4] = hi;
  }
}

// Fused Q/K/V projection: blockIdx.y in 0..5 -> (weight sel, n-half).
__global__ __launch_bounds__(256) void qkv_kernel(
    const float* __restrict__ h,
    const float* __restrict__ wq, const float* __restrict__ bq,
    const float* __restrict__ wk, const float* __restrict__ bk,
    const float* __restrict__ wv, const float* __restrict__ bv,
    float* __restrict__ Q, float* __restrict__ K, float* __restrict__ V)
{
  const int sel = blockIdx.y >> 1;
  const int n0 = (blockIdx.y & 1) * 128;
  const float* W = (sel == 0) ? wq : (sel == 1) ? wk : wv;
  const float* bb = (sel == 0) ? bq : (sel == 1) ? bk : bv;
  float* C = (sel == 0) ? Q : (sel == 1) ? K : V;
  gemm128_core(h, W, bb, C, NTOK, 256, 256, 0, blockIdx.x * 128, n0);
}

// Plain 128x128 GEMM (used for FF1, N=1024, GELU).
__global__ __launch_bounds__(256) void gemm128_kernel(
    const float* __restrict__ A, const float* __restrict__ B,
    const float* __restrict__ bias, float* __restrict__ C,
    int M, int N, int K, int act)
{
  gemm128_core(A, B, bias, C, M, N, K, act, blockIdx.x * 128, blockIdx.y * 128);
}

// ---------------- GEMM 64x64 tile, 4x4 micro, double-buffered LDS -----------
__global__ __launch_bounds__(256) void gemm64_kernel(
    const float* __restrict__ A, const float* __restrict__ B,
    const float* __restrict__ bias, float* __restrict__ C,
    int M, int N, int K, int act)
{
  __shared__ float As[2][16][68];
  __shared__ float Bs[2][16][68];
  const int tid = threadIdx.x;
  const int tx = tid & 15, ty = tid >> 4;
  const int m0 = blockIdx.x * 64, n0 = blockIdx.y * 64;
  const int ar = tid >> 2;
  const int ak = (tid & 3) * 4;
  const int br = tid >> 4;
  const int bn = (tid & 15) * 4;
  const float* Ap = A + (m0 + ar) * K + ak;
  const float* Bp = B + br * N + n0 + bn;
  float acc[4][4] = {};
  float accb[4][4] = {};
  const int nk = K >> 4;

  float4 aR = *(const float4*)(Ap);
  float4 bR = *(const float4*)(Bp);
  As[0][ak + 0][ar] = aR.x; As[0][ak + 1][ar] = aR.y;
  As[0][ak + 2][ar] = aR.z; As[0][ak + 3][ar] = aR.w;
  *(float4*)&Bs[0][br][bn] = bR;

  for (int t = 0; t < nk; t++) {
    const int p = t & 1;
    __syncthreads();
    if (t + 1 < nk) {
      aR = *(const float4*)(Ap + (t + 1) * 16);
      bR = *(const float4*)(Bp + (t + 1) * 16 * N);
    }
#pragma unroll
    for (int kk = 0; kk < 16; kk++) {
      float4 av = *(const float4*)&As[p][kk][ty * 4];
      float4 bv = *(const float4*)&Bs[p][kk][tx * 4];
      float a[4] = {av.x, av.y, av.z, av.w};
      float b[4] = {bv.x, bv.y, bv.z, bv.w};
#pragma unroll
      for (int i = 0; i < 4; i++)
#pragma unroll
        for (int j = 0; j < 4; j++) accb[i][j] = fmaf(a[i], b[j], accb[i][j]);
    }
    if (((((t + 1) << 4) % 384) == 0) || (t + 1 == nk)) {
#pragma unroll
      for (int i = 0; i < 4; i++)
#pragma unroll
        for (int j = 0; j < 4; j++) { acc[i][j] += accb[i][j]; accb[i][j] = 0.f; }
    }
    if (t + 1 < nk) {
      const int q = p ^ 1;
      As[q][ak + 0][ar] = aR.x; As[q][ak + 1][ar] = aR.y;
      As[q][ak + 2][ar] = aR.z; As[q][ak + 3][ar] = aR.w;
      *(float4*)&Bs[q][br][bn] = bR;
    }
  }
  float4 bb4 = make_float4(0.f, 0.f, 0.f, 0.f);
  if (bias) bb4 = *(const float4*)&bias[n0 + tx * 4];
#pragma unroll
  for (int i = 0; i < 4; i++) {
    float4 o;
    o.x = acc[i][0] + bb4.x;
    o.y = acc[i][1] + bb4.y;
    o.z = acc[i][2] + bb4.z;
    o.w = acc[i][3] + bb4.w;
    if (act == 1) {
      o.x = gelu_np(o.x); o.y = gelu_np(o.y);
      o.z = gelu_np(o.z); o.w = gelu_np(o.w);
    }
    *(float4*)&C[(m0 + ty * 4 + i) * N + n0 + tx * 4] = o;
  }
}

// ---------------- attention: branch-free exp, 1 query/thread ----------------
__global__ __launch_bounds__(256) void attn_kernel(
    const float* __restrict__ Q, const float* __restrict__ Kb,
    const float* __restrict__ Vb, float* __restrict__ ctx)
{
  __shared__ float Kc[128][32];
  __shared__ float Vc[128][32];
  const int bh = blockIdx.x;
  const int b = bh >> 3, h = bh & 7;
  const int s = blockIdx.y * 256 + threadIdx.x;
  const int base = (b * 512) * 256 + h * 32;

  float q[32];
  const float* qrow = Q + base + s * 256;
#pragma unroll
  for (int d = 0; d < 32; d += 4) {
    float4 t = *(const float4*)(qrow + d);
    q[d] = t.x; q[d + 1] = t.y; q[d + 2] = t.z; q[d + 3] = t.w;
  }
  float l = 0.f;
  float acc[32] = {};
  const float scale = 0.17677669529663687f;

  for (int kc = 0; kc < 4; kc++) {
#pragma unroll
    for (int r = 0; r < 4; r++) {
      int ff = threadIdx.x + r * 256;
      int j = ff >> 3;
      int d0 = (ff & 7) * 4;
      int tok = kc * 128 + j;
      *(float4*)&Kc[j][d0] = *(const float4*)(Kb + base + tok * 256 + d0);
      *(float4*)&Vc[j][d0] = *(const float4*)(Vb + base + tok * 256 + d0);
    }
    __syncthreads();
#pragma unroll 2
    for (int j = 0; j < 128; j += 2) {
      const float* k0r = &Kc[j][0];
      const float* k1r = &Kc[j + 1][0];
      float a0 = 0.f, a1 = 0.f, a2 = 0.f, a3 = 0.f;
      float b0 = 0.f, b1 = 0.f, b2 = 0.f, b3 = 0.f;
#pragma unroll
      for (int d = 0; d < 32; d += 4) {
        a0 = fmaf(q[d], k0r[d], a0);
        a1 = fmaf(q[d + 1], k0r[d + 1], a1);
        a2 = fmaf(q[d + 2], k0r[d + 2], a2);
        a3 = fmaf(q[d + 3], k0r[d + 3], a3);
        b0 = fmaf(q[d], k1r[d], b0);
        b1 = fmaf(q[d + 1], k1r[d + 1], b1);
        b2 = fmaf(q[d + 2], k1r[d + 2], b2);
        b3 = fmaf(q[d + 3], k1r[d + 3], b3);
      }
      float p0 = expf(((a0 + a1) + (a2 + a3)) * scale);
      float p1 = expf(((b0 + b1) + (b2 + b3)) * scale);
      l += p0;
      l += p1;
      const float* v0r = &Vc[j][0];
      const float* v1r = &Vc[j + 1][0];
#pragma unroll
      for (int d = 0; d < 32; d++)
        acc[d] = fmaf(p1, v1r[d], fmaf(p0, v0r[d], acc[d]));
    }
    __syncthreads();
  }
  float inv = 1.f / l;
  float* crow = ctx + base + s * 256;
#pragma unroll
  for (int d = 0; d < 32; d += 4) {
    float4 o;
    o.x = acc[d] * inv; o.y = acc[d + 1] * inv;
    o.z = acc[d + 2] * inv; o.w = acc[d + 3] * inv;
    *(float4*)(crow + d) = o;
  }
}

// ---------------- fused residual + LayerNorm (numpy-order sums) -------------
__global__ __launch_bounds__(256) void ln_kernel(
    const float* __restrict__ X, const float* __restrict__ R,
    const float* __restrict__ g, const float* __restrict__ bt,
    float* __restrict__ Y, int hasR)
{
  __shared__ float rows[4][256];
  const int w = threadIdx.x >> 6, lane = threadIdx.x & 63;
  const int row = blockIdx.x * 4 + w;
  float4 xv = *(const float4*)(X + row * 256 + lane * 4);
  if (hasR) {
    float4 rv = *(const float4*)(R + row * 256 + lane * 4);
    xv.x += rv.x; xv.y += rv.y; xv.z += rv.z; xv.w += rv.w;
  }
  *(float4*)&rows[w][lane * 4] = xv;
  __syncthreads();
  float sum = np_pairwise256(rows[w], lane);
  float mean = sum * (1.0f / 256.0f);
  float dx = xv.x - mean, dy = xv.y - mean, dz = xv.z - mean, dw = xv.w - mean;
  __syncthreads();
  float4 sq; sq.x = dx * dx; sq.y = dy * dy; sq.z = dz * dz; sq.w = dw * dw;
  *(float4*)&rows[w][lane * 4] = sq;
  __syncthreads();
  float vsum = np_pairwise256(rows[w], lane);
  float var = vsum * (1.0f / 256.0f);
  float inv = 1.0f / sqrtf(var + 1e-5f);
  float4 gv = *(const float4*)(g + lane * 4);
  float4 bv = *(const float4*)(bt + lane * 4);
  float4 o;
  o.x = ((dx * inv) * gv.x) + bv.x;
  o.y = ((dy * inv) * gv.y) + bv.y;
  o.z = ((dz * inv) * gv.z) + bv.z;
  o.w = ((dw * inv) * gv.w) + bv.w;
  *(float4*)(Y + row * 256 + lane * 4) = o;
}

// ---------------- A[t] = sum(h[t]**2) in numpy pairwise order ---------------
__global__ __launch_bounds__(256) void atok_kernel(
    const float* __restrict__ HN, float* __restrict__ Atok)
{
  __shared__ float rows[4][256];
  const int w = threadIdx.x >> 6, lane = threadIdx.x & 63;
  const int row = blockIdx.x * 4 + w;
  float4 v = *(const float4*)&HN[row * 256 + lane * 4];
  float4 sq; sq.x = v.x * v.x; sq.y = v.y * v.y; sq.z = v.z * v.z; sq.w = v.w * v.w;
  *(float4*)&rows[w][lane * 4] = sq;
  __syncthreads();
  float sum = np_pairwise256(rows[w], lane);
  if (lane == 0) Atok[row] = sum;
}

// ---------------- VQ pass 1: 128 tok x 512 codes/block, 8x8 micro -----------
__global__ __launch_bounds__(256) void vq_partial_kernel(
    const float* __restrict__ H, const float* __restrict__ CB,
    const float* __restrict__ Atok, float* __restrict__ partV,
    int* __restrict__ partI)
{
  __shared__ float As[16][132];
  __shared__ float Bs[16][132];
  const int tid = threadIdx.x;
  const int tx = tid & 15, ty = tid >> 4;
  const int m0 = blockIdx.x * 128;
  const int cg0 = blockIdx.y * 512;
  const int ar = tid >> 1;
  const int ak = (tid & 1) * 8;
  float At[8];
#pragma unroll
  for (int i = 0; i < 8; i++) At[i] = Atok[m0 + ty * 8 + i];
  float bestV[8];
  int bestI[8];
#pragma unroll
  for (int i = 0; i < 8; i++) { bestV[i] = FLT_MAX; bestI[i] = 0; }

  for (int ct = 0; ct < 4; ct++) {
    const int c0 = cg0 + ct * 128;
    float acc[8][8] = {};
    const float* Ap = H + (m0 + ar) * 256 + ak;
    const float* Bp = CB + (c0 + ar) * 256 + ak;
    for (int k0 = 0; k0 < 256; k0 += 16) {
      float4 a0 = *(const float4*)(Ap);
      float4 a1 = *(const float4*)(Ap + 4);
      float4 c0v = *(const float4*)(Bp);
      float4 c1v = *(const float4*)(Bp + 4);
      As[ak + 0][ar] = a0.x; As[ak + 1][ar] = a0.y;
      As[ak + 2][ar] = a0.z; As[ak + 3][ar] = a0.w;
      As[ak + 4][ar] = a1.x; As[ak + 5][ar] = a1.y;
      As[ak + 6][ar] = a1.z; As[ak + 7][ar] = a1.w;
      Bs[ak + 0][ar] = c0v.x; Bs[ak + 1][ar] = c0v.y;
      Bs[ak + 2][ar] = c0v.z; Bs[ak + 3][ar] = c0v.w;
      Bs[ak + 4][ar] = c1v.x; Bs[ak + 5][ar] = c1v.y;
      Bs[ak + 6][ar] = c1v.z; Bs[ak + 7][ar] = c1v.w;
      __syncthreads();
#pragma unroll
      for (int kk = 0; kk < 16; kk++) {
        float4 av0 = *(const float4*)&As[kk][ty * 8];
        float4 av1 = *(const float4*)&As[kk][ty * 8 + 4];
        float4 bv0 = *(const float4*)&Bs[kk][tx * 4];       // 2-way: free
        float4 bv1 = *(const float4*)&Bs[kk][64 + tx * 4];  // 2-way: free
        float a[8] = {av0.x, av0.y, av0.z, av0.w, av1.x, av1.y, av1.z, av1.w};
        float b[8] = {bv0.x, bv0.y, bv0.z, bv0.w, bv1.x, bv1.y, bv1.z, bv1.w};
#pragma unroll
        for (int i = 0; i < 8; i++)
#pragma unroll
          for (int j = 0; j < 8; j++) acc[i][j] = fmaf(a[i], b[j], acc[i][j]);
      }
      __syncthreads();
      Ap += 16;
      Bp += 16;
    }
#pragma unroll
    for (int i = 0; i < 8; i++) {
#pragma unroll
      for (int j = 0; j < 8; j++) {
        // lane's codes ascend: tx*4+0..3 then 64+tx*4+0..3 (strict < keeps
        // lowest-index within lane; cross-lane reduce handles the rest)
        int code = c0 + ((j < 4) ? (tx * 4 + j) : (64 + tx * 4 + (j - 4)));
        float v = At[i] - 2.0f * acc[i][j];  // fl(A - 2*acc), single rounding
        if (v < bestV[i]) { bestV[i] = v; bestI[i] = code; }
      }
    }
  }
#pragma unroll
  for (int i = 0; i < 8; i++) {
    float v = bestV[i];
    int ii = bestI[i];
#pragma unroll
    for (int off = 1; off < 16; off <<= 1) {
      float ov = __shfl_xor(v, off);
      int oi = __shfl_xor(ii, off);
      if (ov < v || (ov == v && oi < ii)) { v = ov; ii = oi; }
    }
    if (tx == 0) {
      int token = m0 + ty * 8 + i;
      partV[token * 16 + blockIdx.y] = v;
      partI[token * 16 + blockIdx.y] = ii;
    }
  }
}

// ---------------- VQ pass 2: final argmin, gather, loss, histogram ----------
__global__ __launch_bounds__(256) void vq_final_kernel(
    const float* __restrict__ partV, const int* __restrict__ partI,
    const float* __restrict__ HN, const float* __restrict__ CB,
    float* __restrict__ outQuant, float* __restrict__ outIdxF,
    int* __restrict__ idxInt, int* __restrict__ counts,
    float* __restrict__ lossAcc)
{
  const int w = threadIdx.x >> 6, lane = threadIdx.x & 63;
  const int t = blockIdx.x * 4 + w;
  float v = (lane < 16) ? partV[t * 16 + lane] : FLT_MAX;
  int i = (lane < 16) ? partI[t * 16 + lane] : 0x7fffffff;
#pragma unroll
  for (int off = 8; off; off >>= 1) {
    float ov = __shfl_xor(v, off);
    int oi = __shfl_xor(i, off);
    if (ov < v || (ov == v && oi < i)) { v = ov; i = oi; }
  }
  int idx = __shfl(i, 0);
  const float* c = CB + idx * 256;
  const float* hh = HN + t * 256;
  float4 cv = *(const float4*)(c + lane * 4);
  float4 hv = *(const float4*)(hh + lane * 4);
  *(float4*)(outQuant + t * 256 + lane * 4) = cv;
  float ex = cv.x - hv.x, ey = cv.y - hv.y, ez = cv.z - hv.z, ew = cv.w - hv.w;
  float se = ex * ex + ey * ey + ez * ez + ew * ew;
#pragma unroll
  for (int off = 32; off; off >>= 1) se += __shfl_xor(se, off);
  if (lane == 0) {
    outIdxF[t] = (float)idx;
    idxInt[t] = idx;
    atomicAdd(&counts[idx], 1);
    atomicAdd(lossAcc, se);
  }
}

// ---------------- VQ stats: loss finalize + perplexity ----------------------
__global__ __launch_bounds__(256) void vq_stats_kernel(
    const int* __restrict__ counts, const float* __restrict__ lossAcc,
    float* __restrict__ out)
{
  float ent = 0.f;
  for (int k = threadIdx.x; k < 8192; k += 256) {
    float p = (float)counts[k] * (1.0f / 8192.0f);
    ent += p * logf(p + 1e-10f);
  }
#pragma unroll
  for (int off = 32; off; off >>= 1) ent += __shfl_xor(ent, off);
  __shared__ float ws4[4];
  const int w = threadIdx.x >> 6, lane = threadIdx.x & 63;
  if (lane == 0) ws4[w] = ent;
  __syncthreads();
  if (threadIdx.x == 0) {
    float e = ws4[0] + ws4[1] + ws4[2] + ws4[3];
    out[2097152] = 1.25f * lossAcc[0] * (1.0f / 2097152.0f);
    out[2097153] = expf(-e);
  }
}

__global__ void zero_kernel(int* __restrict__ counts, float* __restrict__ lossAcc) {
  int i = blockIdx.x * 256 + threadIdx.x;
  if (i < 8192) counts[i] = 0;
  if (i == 0) lossAcc[0] = 0.f;
}

extern "C" void kernel_launch(void* const* d_in, const int* in_sizes, int n_in,
                              void* d_out, int out_size, void* d_ws, size_t ws_size,
                              hipStream_t stream) {
  const float* x = (const float*)d_in[0];
  const float* w_in = (const float*)d_in[1];
  const float* b_in = (const float*)d_in[2];
  const float* wq = (const float*)d_in[3];
  const float* bq = (const float*)d_in[4];
  const float* wk = (const float*)d_in[5];
  const float* bk = (const float*)d_in[6];
  const float* wv = (const float*)d_in[7];
  const float* bv = (const float*)d_in[8];
  const float* wo = (const float*)d_in[9];
  const float* bo = (const float*)d_in[10];
  const float* ln1g = (const float*)d_in[11];
  const float* ln1b = (const float*)d_in[12];
  const float* ln2g = (const float*)d_in[13];
  const float* ln2b = (const float*)d_in[14];
  const float* ff1w = (const float*)d_in[15];
  const float* ff1b = (const float*)d_in[16];
  const float* ff2w = (const float*)d_in[17];
  const float* ff2b = (const float*)d_in[18];
  const float* preg = (const float*)d_in[19];
  const float* preb = (const float*)d_in[20];
  const float* cb = (const float*)d_in[21];
  float* out = (float*)d_out;

  if (ws_size < (51ull << 20)) return;
  char* ws = (char*)d_ws;
  float* h = (float*)(ws + 0);                    // 8MB [8192,256]
  float* Qb = (float*)(ws + (8ull << 20));        // 8MB
  float* Kb2 = (float*)(ws + (16ull << 20));      // 8MB
  float* Vb = (float*)(ws + (24ull << 20));       // 8MB
  float* Cx = (float*)(ws + (32ull << 20));       // 8MB
  float* Ob = Qb;                                 // alias (Q dead after attn)
  float* F1 = Qb;                                 // alias 8..40MB [8192,1024]
  float* F2 = (float*)(ws + (40ull << 20));       // 8MB
  float* HN = F2;                                 // alias (F2 dead after ln2)
  float* Atok = (float*)(ws + (48ull << 20));     // 32KB
  float* partV = (float*)(ws + (49ull << 20));    // 512KB
  int* partI = (int*)(ws + (49ull << 20) + (512ull << 10));  // 512KB
  int* idxInt = (int*)(ws + (50ull << 20));       // 32KB
  int* counts = (int*)(ws + (50ull << 20) + (64ull << 10));  // 32KB
  float* lossAcc = (float*)(ws + (50ull << 20) + (128ull << 10));

  zero_kernel<<<32, 256, 0, stream>>>(counts, lossAcc);

  // h = x @ w_in + b_in   [8192,512]x[512,256]
  gemm64_kernel<<<dim3(128, 4), 256, 0, stream>>>(x, w_in, b_in, h, NTOK, 256, 512, 0);

  for (int i = 0; i < 3; i++) {
    qkv_kernel<<<dim3(64, 6), 256, 0, stream>>>(
        h, wq + i * 65536, bq + i * 256, wk + i * 65536, bk + i * 256,
        wv + i * 65536, bv + i * 256, Qb, Kb2, Vb);
    attn_kernel<<<dim3(128, 2), 256, 0, stream>>>(Qb, Kb2, Vb, Cx);
    gemm64_kernel<<<dim3(128, 4), 256, 0, stream>>>(Cx, wo + i * 65536, bo + i * 256, Ob, NTOK, 256, 256, 0);
    ln_kernel<<<2048, 256, 0, stream>>>(h, Ob, ln1g + i * 256, ln1b + i * 256, h, 1);
    gemm128_kernel<<<dim3(64, 8), 256, 0, stream>>>(h, ff1w + i * 262144, ff1b + i * 1024, F1, NTOK, 1024, 256, 1);
    gemm64_kernel<<<dim3(128, 4), 256, 0, stream>>>(F1, ff2w + i * 262144, ff2b + i * 256, F2, NTOK, 256, 1024, 0);
    ln_kernel<<<2048, 256, 0, stream>>>(h, F2, ln2g + i * 256, ln2b + i * 256, h, 1);
  }
  ln_kernel<<<2048, 256, 0, stream>>>(h, nullptr, preg, preb, HN, 0);

  atok_kernel<<<2048, 256, 0, stream>>>(HN, Atok);
  vq_partial_kernel<<<dim3(64, 16), 256, 0, stream>>>(HN, cb, Atok, partV, partI);
  vq_final_kernel<<<2048, 256, 0, stream>>>(partV, partI, HN, cb,
                                            out, out + 2097154, idxInt, counts, lossAcc);
  vq_stats_kernel<<<1, 256, 0, stream>>>(counts, lossAcc, out);
}